// Round 1
// 157.569 us; speedup vs baseline: 1.0193x; 1.0193x over previous
//
#include <hip/hip_runtime.h>

// HydrophobicPairs: E[b,l] = h[seq[b,l]] * sum_k h[seq[b, j_idx[b,l,k]]] * g(r[b,l,k])
// g(r) = exp(-(r_c - r_peak)^2 / (2 sigma^2)) * (r < md - 1e-4)
// B=32, L=8192, K=64, NUM_AA=20.
//
// R9: R2-R8 pinned at 45-51us with every pipe <25% and ~4.4 B/cyc/CU ingress.
// Little's law on R8's DMA scheme: only ~3 KB/wave in flight (2-chunk-ahead,
// stores polluting vmcnt) -> ~48 KB/CU -> effective loaded latency ~11k cyc.
// No prior round provably had a deep pipe (R2-R7 VGPR prefetch collapsed per
// VGPR_Count 24-32; R8 structurally 2-ahead). This round forces depth the
// compiler cannot collapse: inline-asm global_load_dwordx4 register staging,
// DEPTH=6 chunks ahead = 12 outstanding loads = 12 KB/wave x 16 waves =
// 192 KB/CU in flight (4x R8). Hand-counted s_waitcnt vmcnt(N) on a
// loads-only queue (per-chunk stores moved to an LDS stash, flushed once at
// the end), sched_barrier(0) after each wait (rule #18). r/j no longer
// round-trip LDS at all; LDS is h_row gather only.

#define BB 32
#define LL 8192
#define KK 64
#define TPB 512
#define RPB 512          // rows per block -> 512 blocks, 2/CU, 16 waves/CU
#define NWAVE 8
#define NCHUNK 16        // 16 chunks x 4 rows = 64 rows per wave
#define DEPTH 6          // chunks in flight per wave (12 loads, 12 KB)

typedef float f32x4 __attribute__((ext_vector_type(4)));
typedef int   i32x4 __attribute__((ext_vector_type(4)));

// Sum across each 16-lane row via DPP row_shr (VALU-only). bound_ctrl=1
// zero-fills. Result lands in lane 15 of each 16-lane group.
__device__ __forceinline__ float row16_sum(float x) {
    x += __int_as_float(__builtin_amdgcn_mov_dpp(__float_as_int(x), 0x111, 0xF, 0xF, true)); // row_shr:1
    x += __int_as_float(__builtin_amdgcn_mov_dpp(__float_as_int(x), 0x112, 0xF, 0xF, true)); // row_shr:2
    x += __int_as_float(__builtin_amdgcn_mov_dpp(__float_as_int(x), 0x114, 0xF, 0xF, true)); // row_shr:4
    x += __int_as_float(__builtin_amdgcn_mov_dpp(__float_as_int(x), 0x118, 0xF, 0xF, true)); // row_shr:8
    return x;
}

// Issue one chunk's pair of 16 B/lane loads into register staging.
// volatile asm: ordered among themselves and vs the waitcnt asms below.
#define ISSUE(c) do {                                                          \
    asm volatile("global_load_dwordx4 %0, %1, off"                             \
                 : "=v"(rs[c]) : "v"(rlane + (c) * 256));                      \
    asm volatile("global_load_dwordx4 %0, %1, off"                             \
                 : "=v"(js[c]) : "v"(jlane + (c) * 256));                      \
} while (0)

// Hand-counted wait on the loads-only vmcnt queue; sched_barrier(0) stops
// hipcc hoisting register-only consumers above the wait (rule #18).
#define WAITV(n) do {                                                          \
    asm volatile("s_waitcnt vmcnt(" #n ")" ::: "memory");                      \
    __builtin_amdgcn_sched_barrier(0);                                         \
} while (0)

__global__ __launch_bounds__(TPB, 4) void _HydrophobicPairs_58256936403302_kernel(
    const int*   __restrict__ seq,        // [B,L]
    const float* __restrict__ r,          // [B,L,K]
    const int*   __restrict__ j_idx,      // [B,L,K]
    const float* __restrict__ h,          // [20]
    const float* __restrict__ r_half_raw, // [1]
    const float* __restrict__ tau_hp_raw, // [1]
    const int*   __restrict__ max_dist,   // [1]
    float*       __restrict__ out)        // [B,L]
{
    __shared__ float h_row[LL];           // 32 KB
    __shared__ float res[NWAVE][64];      // 2 KB result stash (per-wave rows)

    const int tid  = threadIdx.x;
    const int wave = tid >> 6;
    const int lane = tid & 63;
    const int b     = blockIdx.x >> 4;    // 16 chunks of 512 rows per b
    const int lbase = (blockIdx.x & 15) * RPB;

    // Stage h[seq[b, :]] -> LDS (coalesced int4 reads; h is 80 B, L1-hot).
    const int4* seq4 = (const int4*)(seq + b * LL);
    #pragma unroll
    for (int i = 0; i < 4; ++i) {
        const int e4 = i * TPB + tid;     // 0..2047 int4s
        const int4 s = seq4[e4];
        ((float4*)h_row)[e4] = make_float4(h[s.x], h[s.y], h[s.z], h[s.w]);
    }

    // Runtime scalars (broadcast, cached).
    const float md     = (float)max_dist[0];
    const float r_peak = log1pf(expf(r_half_raw[0]));            // softplus
    const float sigma  = log1pf(expf(tau_hp_raw[0])) + 0.1f;
    const float nscale = -1.44269504f / (2.0f * sigma * sigma);  // -log2e/(2s^2)
    const float c1     = -2.0f * nscale * r_peak;
    const float c0     = nscale * r_peak * r_peak;
    const float vthr   = md - 1e-4f;

    // Barrier: h_row visible; compiler drains vmcnt to 0 here, so the asm
    // load queue below starts from a clean count.
    __syncthreads();

    // Per-wave stream: 64 rows at l0; chunk = 4 rows = 256 elems = 1 KB each
    // of r/j; lane covers elements [4*lane, 4*lane+4) of each chunk.
    const int l0 = lbase + wave * 64;
    const float* rlane = r     + (size_t)(b * LL + l0) * KK + (lane << 2);
    const int*   jlane = j_idx + (size_t)(b * LL + l0) * KK + (lane << 2);

    f32x4 rs[NCHUNK];                     // register staging (SROA'd: all
    i32x4 js[NCHUNK];                     // indices compile-time constant)

    // Prologue: chunks 0..DEPTH-1 in flight (12 loads, 12 KB/lane-group).
    #pragma unroll
    for (int p = 0; p < DEPTH; ++p) ISSUE(p);

    const int myrow = lane >> 4;          // 0..3 (row within chunk)
    const int klane = lane & 15;

    #pragma unroll
    for (int c = 0; c < NCHUNK; ++c) {
        // Loads retire in order; queue holds chunks c..c+DEPTH-1.
        // Wait N = 2*min(DEPTH-1, 15-c): chunk c's pair has landed.
        if      (c <= NCHUNK - DEPTH) WAITV(10);
        else if (c == 11)             WAITV(8);
        else if (c == 12)             WAITV(6);
        else if (c == 13)             WAITV(4);
        else if (c == 14)             WAITV(2);
        else                          WAITV(0);

        // Refill the pipe immediately after the wait.
        if (c + DEPTH < NCHUNK) ISSUE(c + DEPTH);

        const f32x4 rc = rs[c];
        const i32x4 jc = js[c];

        float acc = 0.0f;
        #pragma unroll
        for (int u = 0; u < 4; ++u) {
            const float rv = rc[u];
            const unsigned j = (unsigned)jc[u] & (LL - 1);
            const float hj = h_row[j];                        // LDS gather
            const float uexp = fmaf(rv, fmaf(nscale, rv, c1), c0);
            float g = exp2f(uexp);                            // v_exp_f32
            g = (rv < vthr) ? g : 0.0f;                       // validity mask
            acc = fmaf(hj, g, acc);
        }

        acc = row16_sum(acc);             // sum over the 16 k-lanes

        // Stash in LDS (DS op: does not touch the vmcnt queue). Same-wave
        // LDS ops execute in order -> no barrier needed before the flush.
        if (klane == 15) res[wave][(c << 2) | myrow] = acc;
    }

    // Flush: one coalesced 256 B store per wave.
    const int lrow = l0 + lane;
    out[b * LL + lrow] = h_row[lrow] * res[wave][lane];
}

extern "C" void kernel_launch(void* const* d_in, const int* in_sizes, int n_in,
                              void* d_out, int out_size, void* d_ws, size_t ws_size,
                              hipStream_t stream) {
    const int*   seq        = (const int*)d_in[0];
    const float* r          = (const float*)d_in[1];
    const int*   j_idx      = (const int*)d_in[2];
    const float* h          = (const float*)d_in[3];
    const float* r_half_raw = (const float*)d_in[4];
    const float* tau_hp_raw = (const float*)d_in[5];
    const int*   max_dist   = (const int*)d_in[6];
    float*       out        = (float*)d_out;

    // 512 blocks x 512 threads: 2 blocks/CU (34 KB LDS each), 16 waves/CU.
    _HydrophobicPairs_58256936403302_kernel<<<dim3(BB * (LL / RPB)), dim3(TPB), 0, stream>>>(
        seq, r, j_idx, h, r_half_raw, tau_hp_raw, max_dist, out);
}